// Round 1
// baseline (2450.354 us; speedup 1.0000x reference)
//
#include <hip/hip_runtime.h>
#include <math.h>

// Problem sizes (fixed by reference)
#define Bq 1024
#define Nn 128
#define Mm 8192
#define Ss 256

// Main-kernel tiling
#define BT 64     // b-tile per block
#define MT 128    // m-subtile
#define NSUB 2    // m-subtiles per block (block covers 256 m)
#define NC 16     // n-chunk staged in LDS

#define PI_F 3.14159265358979323846f
#define INV_SQRT_PI 0.5641895835477563f
#define TINY_F 1.17549435e-38f
#define EPS_TOTAL 1e-3f

// Workspace layout (float offsets)
#define WS_OUTACC 0
#define WS_DEN    (Bq*Ss*2)
#define WS_Z2     (WS_DEN + Bq)
#define WS_DUR    (WS_Z2 + Bq)
#define WS_DUI    (WS_DUR + Bq*Nn)
#define WS_DJR    (WS_DUI + Bq*Nn)
#define WS_DJI    (WS_DJR + Mm*Nn)
#define WS_C1     (WS_DJI + Mm*Nn)
#define WS_C2     (WS_C1 + Mm)
#define WS_ZJ2    (WS_C2 + Mm)
#define WS_ISP    (WS_ZJ2 + Mm)
#define WS_ISQ    (WS_ISP + Mm)
#define WS_COEF   (WS_ISQ + Mm)
#define WS_SCALE  (WS_COEF + Mm)

// ---------------- prep over b: normalize d, |z|^2 ----------------
__global__ void cpsf_prep_b(const float* __restrict__ z_re, const float* __restrict__ z_im,
                            const float* __restrict__ d_re, const float* __restrict__ d_im,
                            float* __restrict__ ws)
{
    const int b = blockIdx.x * 4 + (threadIdx.x >> 6);
    const int l = threadIdx.x & 63;
    const int o = b * Nn;
    float dr0 = d_re[o + l], dr1 = d_re[o + l + 64];
    float di0 = d_im[o + l], di1 = d_im[o + l + 64];
    float zr0 = z_re[o + l], zr1 = z_re[o + l + 64];
    float zi0 = z_im[o + l], zi1 = z_im[o + l + 64];
    float sd = dr0*dr0 + di0*di0 + dr1*dr1 + di1*di1;
    float sz = zr0*zr0 + zi0*zi0 + zr1*zr1 + zi1*zi1;
#pragma unroll
    for (int off = 1; off < 64; off <<= 1) {
        sd += __shfl_xor(sd, off);
        sz += __shfl_xor(sz, off);
    }
    float nd = sqrtf(sd);
    nd = (nd == 0.0f) ? 1.0f : nd;
    float inv = 1.0f / nd;
    ws[WS_DUR + o + l]      = dr0 * inv;
    ws[WS_DUR + o + l + 64] = dr1 * inv;
    ws[WS_DUI + o + l]      = di0 * inv;
    ws[WS_DUI + o + l + 64] = di1 * inv;
    if (l == 0) ws[WS_Z2 + b] = sz;
}

// ---------------- prep over m: normalize d_j, fold constants ----------------
__global__ void cpsf_prep_m(const float* __restrict__ zj_re, const float* __restrict__ zj_im,
                            const float* __restrict__ dj_re, const float* __restrict__ dj_im,
                            const float* __restrict__ alpha, const float* __restrict__ sp_,
                            const float* __restrict__ sq_, float* __restrict__ ws)
{
    const int m = blockIdx.x * 4 + (threadIdx.x >> 6);
    const int l = threadIdx.x & 63;
    const int o = m * Nn;
    float dr0 = dj_re[o + l], dr1 = dj_re[o + l + 64];
    float di0 = dj_im[o + l], di1 = dj_im[o + l + 64];
    float zr0 = zj_re[o + l], zr1 = zj_re[o + l + 64];
    float zi0 = zj_im[o + l], zi1 = zj_im[o + l + 64];
    float snd = dr0*dr0 + di0*di0 + dr1*dr1 + di1*di1;
    float sc1 = dr0*zr0 + di0*zi0 + dr1*zr1 + di1*zi1;
    float sc2 = dr0*zi0 - di0*zr0 + dr1*zi1 - di1*zr1;
    float sz2 = zr0*zr0 + zi0*zi0 + zr1*zr1 + zi1*zi1;
#pragma unroll
    for (int off = 1; off < 64; off <<= 1) {
        snd += __shfl_xor(snd, off);
        sc1 += __shfl_xor(sc1, off);
        sc2 += __shfl_xor(sc2, off);
        sz2 += __shfl_xor(sz2, off);
    }
    float nd = sqrtf(snd);
    nd = (nd == 0.0f) ? 1.0f : nd;
    float inv = 1.0f / nd;
    ws[WS_DJR + o + l]      = dr0 * inv;
    ws[WS_DJR + o + l + 64] = dr1 * inv;
    ws[WS_DJI + o + l]      = di0 * inv;
    ws[WS_DJI + o + l + 64] = di1 * inv;
    if (l == 0) {
        ws[WS_C1 + m]  = sc1 * inv;
        ws[WS_C2 + m]  = sc2 * inv;
        ws[WS_ZJ2 + m] = sz2;
        float sp = fmaxf(sp_[m], TINY_F);
        float sq = fmaxf(sq_[m], TINY_F);
        float sc = sqrtf(sp / PI_F);
        ws[WS_ISP + m]   = PI_F / sp;
        ws[WS_ISQ + m]   = PI_F / sq;
        ws[WS_SCALE + m] = sc;
        ws[WS_COEF + m]  = fmaxf(alpha[m], TINY_F) * sc * INV_SQRT_PI;
    }
}

// ---------------- fused main: 5 dot-maps + GH epilogue + partial w@T ----------------
__global__ __launch_bounds__(512, 2) void cpsf_main(
    const float* __restrict__ z_re, const float* __restrict__ z_im,
    const float* __restrict__ zj_re, const float* __restrict__ zj_im,
    const float* __restrict__ T_re, const float* __restrict__ T_im,
    float* __restrict__ ws)
{
    // LDS: staging planes (reused as w-tile between phases)
    // lz: 4 planes [NC][64]   -> 4096 floats
    // lm: 4 planes [NC][128]  -> 8192 floats
    // lw: [64][132]           -> 8448 floats (overlaps lz/lm, barrier-separated)
    __shared__ __align__(16) float smem[12288];
    float* lz = smem;
    float* lm = smem + 4096;
    float* lw = smem;

    const float* dur = ws + WS_DUR;
    const float* dui = ws + WS_DUI;
    const float* djr = ws + WS_DJR;
    const float* dji = ws + WS_DJI;

    const int tid = threadIdx.x;
    const int b0 = blockIdx.y * BT;
    const int msuper0 = blockIdx.x * (MT * NSUB);

    // phase-1 mapping: 32x16 threads, each 4m x 4b
    const int m4 = (tid & 31) * 4;
    const int b4 = (tid >> 5) * 4;
    // phase-4 mapping: 16 b-quads x 32 s-groups
    const int b4p = (tid & 15) * 4;
    const int sbase = (tid >> 4) * 4;

    const float GT[8] = {-2.9306374202572440f, -1.9816567566958429f,
                         -1.1571937124467802f, -0.3811869902073221f,
                          0.3811869902073221f,  1.1571937124467802f,
                          1.9816567566958429f,  2.9306374202572440f};
    const float GW[8] = {1.9960407221136762e-04f, 1.7077983007413475e-02f,
                         2.0780232581489188e-01f, 6.6114701255824129e-01f,
                         6.6114701255824129e-01f, 2.0780232581489188e-01f,
                         1.7077983007413475e-02f, 1.9960407221136762e-04f};

    float aR[32], aI[32];
#pragma unroll
    for (int i = 0; i < 32; ++i) { aR[i] = 0.0f; aI[i] = 0.0f; }

    float z2b[4];
#pragma unroll
    for (int bb = 0; bb < 4; ++bb) z2b[bb] = ws[WS_Z2 + b0 + b4 + bb];

    for (int ms = 0; ms < NSUB; ++ms) {
        const int m0 = msuper0 + ms * MT;
        float a0[16], a1[16], a2[16], a3[16], a4[16];
#pragma unroll
        for (int i = 0; i < 16; ++i) { a0[i]=0.f; a1[i]=0.f; a2[i]=0.f; a3[i]=0.f; a4[i]=0.f; }

        for (int nk = 0; nk < Nn; nk += NC) {
            __syncthreads();
            // stage z-side: 1024 float4 (4 arrays x 64 rows x 4)
#pragma unroll
            for (int it = 0; it < 2; ++it) {
                int i = tid + it * 512;
                int arr = i >> 8, rem = i & 255, row = rem >> 2, j4 = rem & 3;
                const float* p = (arr == 0) ? z_re : (arr == 1) ? z_im : (arr == 2) ? dur : dui;
                float4 v = *(const float4*)(p + (b0 + row) * Nn + nk + j4 * 4);
                float* d = lz + arr * 1024 + (j4 * 4) * 64 + row;
                d[0] = v.x; d[64] = v.y; d[128] = v.z; d[192] = v.w;
            }
            // stage m-side: 2048 float4 (4 arrays x 128 rows x 4)
#pragma unroll
            for (int it = 0; it < 4; ++it) {
                int i = tid + it * 512;
                int arr = i >> 9, rem = i & 511, row = rem >> 2, j4 = rem & 3;
                const float* p = (arr == 0) ? djr : (arr == 1) ? dji : (arr == 2) ? zj_re : zj_im;
                float4 v = *(const float4*)(p + (m0 + row) * Nn + nk + j4 * 4);
                float* d = lm + arr * 2048 + (j4 * 4) * 128 + row;
                d[0] = v.x; d[128] = v.y; d[256] = v.z; d[384] = v.w;
            }
            __syncthreads();
#pragma unroll
            for (int j = 0; j < NC; ++j) {
                float zr[4], zi[4], ur[4], ui[4], mr[4], mi[4], qr[4], qi[4];
                *(float4*)zr = *(const float4*)(lz +        j * 64 + b4);
                *(float4*)zi = *(const float4*)(lz + 1024 + j * 64 + b4);
                *(float4*)ur = *(const float4*)(lz + 2048 + j * 64 + b4);
                *(float4*)ui = *(const float4*)(lz + 3072 + j * 64 + b4);
                *(float4*)mr = *(const float4*)(lm +        j * 128 + m4);
                *(float4*)mi = *(const float4*)(lm + 2048 + j * 128 + m4);
                *(float4*)qr = *(const float4*)(lm + 4096 + j * 128 + m4);
                *(float4*)qi = *(const float4*)(lm + 6144 + j * 128 + m4);
#pragma unroll
                for (int bb = 0; bb < 4; ++bb) {
#pragma unroll
                    for (int mm = 0; mm < 4; ++mm) {
                        int x = bb * 4 + mm;
                        a0[x] += zr[bb] * mr[mm] + zi[bb] * mi[mm];  // S1 (pr raw)
                        a1[x] += zi[bb] * mr[mm] - zr[bb] * mi[mm];  // S2 (pi raw)
                        a2[x] += zr[bb] * qr[mm] + zi[bb] * qi[mm];  // S3 (z.zj)
                        a3[x] += ur[bb] * mr[mm] + ui[bb] * mi[mm];  // ar
                        a4[x] += ui[bb] * mr[mm] - ur[bb] * mi[mm];  // ai
                    }
                }
            }
        }
        __syncthreads();
        // phase 2: per-pair epilogue -> w into LDS tile [b][m]
#pragma unroll
        for (int mm = 0; mm < 4; ++mm) {
            int mg = m0 + m4 + mm;
            float c1  = ws[WS_C1 + mg],  c2  = ws[WS_C2 + mg];
            float zj2 = ws[WS_ZJ2 + mg], isp = ws[WS_ISP + mg];
            float isq = ws[WS_ISQ + mg], cf  = ws[WS_COEF + mg];
            float sc  = ws[WS_SCALE + mg];
#pragma unroll
            for (int bb = 0; bb < 4; ++bb) {
                int x = bb * 4 + mm;
                float prv = a0[x] - c1;
                float piv = a1[x] - c2;
                float dz2 = z2b[bb] + zj2 - 2.0f * a2[x];
                float perp2 = fmaxf(dz2 - prv * prv - piv * piv, 0.0f);
                float basee = -(isq * perp2 + isp * piv * piv);
                float rho = 0.0f;
#pragma unroll
                for (int k = 0; k < 8; ++k) {
                    float dd = prv - sc * GT[k];
                    rho = fmaf(GW[k], __expf(basee - isp * dd * dd), rho);
                }
                float arv = a3[x], aiv = a4[x];
                lw[(b4 + bb) * 132 + m4 + mm] = cf * (arv * arv + aiv * aiv) * rho;
            }
        }
        __syncthreads();
        // den partial (one row per lane of wave 0)
        if (tid < BT) {
            float s = 0.0f;
            for (int mI = 0; mI < MT; ++mI) s += lw[tid * 132 + mI];
            atomicAdd(ws + WS_DEN + b0 + tid, s);
        }
        // phase 4: partial w @ T, accumulate in registers across subtiles
        for (int mI = 0; mI < MT; ++mI) {
            float w[4];
            w[0] = lw[(b4p + 0) * 132 + mI];
            w[1] = lw[(b4p + 1) * 132 + mI];
            w[2] = lw[(b4p + 2) * 132 + mI];
            w[3] = lw[(b4p + 3) * 132 + mI];
            const float* tb = T_re + (m0 + mI) * Ss + sbase;
            const float* ub = T_im + (m0 + mI) * Ss + sbase;
            float t0[4], t1[4], u0[4], u1[4];
            *(float4*)t0 = *(const float4*)(tb);
            *(float4*)t1 = *(const float4*)(tb + 128);
            *(float4*)u0 = *(const float4*)(ub);
            *(float4*)u1 = *(const float4*)(ub + 128);
#pragma unroll
            for (int bb = 0; bb < 4; ++bb) {
#pragma unroll
                for (int ss = 0; ss < 4; ++ss) {
                    aR[bb * 4 + ss]      = fmaf(w[bb], t0[ss], aR[bb * 4 + ss]);
                    aR[16 + bb * 4 + ss] = fmaf(w[bb], t1[ss], aR[16 + bb * 4 + ss]);
                    aI[bb * 4 + ss]      = fmaf(w[bb], u0[ss], aI[bb * 4 + ss]);
                    aI[16 + bb * 4 + ss] = fmaf(w[bb], u1[ss], aI[16 + bb * 4 + ss]);
                }
            }
        }
    }
    // epilogue: one atomic pass
    float* oa = ws + WS_OUTACC;
#pragma unroll
    for (int so = 0; so < 2; ++so) {
#pragma unroll
        for (int bb = 0; bb < 4; ++bb) {
#pragma unroll
            for (int ss = 0; ss < 4; ++ss) {
                int b = b0 + b4p + bb;
                int s = sbase + so * 128 + ss;
                atomicAdd(oa + (b * Ss + s) * 2 + 0, aR[so * 16 + bb * 4 + ss]);
                atomicAdd(oa + (b * Ss + s) * 2 + 1, aI[so * 16 + bb * 4 + ss]);
            }
        }
    }
}

// ---------------- finalize: divide by den ----------------
__global__ void cpsf_fin(const float* __restrict__ ws, float* __restrict__ out)
{
    int i = blockIdx.x * 512 + threadIdx.x;
    float den = ws[WS_DEN + (i >> 9)] + EPS_TOTAL;
    out[i] = ws[WS_OUTACC + i] / den;
}

extern "C" void kernel_launch(void* const* d_in, const int* in_sizes, int n_in,
                              void* d_out, int out_size, void* d_ws, size_t ws_size,
                              hipStream_t stream)
{
    (void)in_sizes; (void)n_in; (void)out_size; (void)ws_size;
    const float* z_re  = (const float*)d_in[0];
    const float* z_im  = (const float*)d_in[1];
    const float* d_re  = (const float*)d_in[2];
    const float* d_im  = (const float*)d_in[3];
    const float* zj_re = (const float*)d_in[4];
    const float* zj_im = (const float*)d_in[5];
    const float* dj_re = (const float*)d_in[6];
    const float* dj_im = (const float*)d_in[7];
    const float* T_re  = (const float*)d_in[8];
    const float* T_im  = (const float*)d_in[9];
    const float* alpha = (const float*)d_in[10];
    const float* s_par = (const float*)d_in[11];
    const float* s_perp= (const float*)d_in[12];
    float* ws = (float*)d_ws;

    // zero the accumulators (out_acc + den)
    hipMemsetAsync(d_ws, 0, (size_t)(Bq * Ss * 2 + Bq) * sizeof(float), stream);

    cpsf_prep_b<<<Bq / 4, 256, 0, stream>>>(z_re, z_im, d_re, d_im, ws);
    cpsf_prep_m<<<Mm / 4, 256, 0, stream>>>(zj_re, zj_im, dj_re, dj_im, alpha, s_par, s_perp, ws);
    cpsf_main<<<dim3(Mm / (MT * NSUB), Bq / BT), 512, 0, stream>>>(
        z_re, z_im, zj_re, zj_im, T_re, T_im, ws);
    cpsf_fin<<<(Bq * Ss * 2) / 512, 512, 0, stream>>>(ws, (float*)d_out);
}

// Round 2
// 896.325 us; speedup vs baseline: 2.7338x; 2.7338x over previous
//
#include <hip/hip_runtime.h>
#include <math.h>

// Problem sizes (fixed by reference)
#define Bq 1024
#define Nn 128
#define Mm 8192
#define Ss 256
#define Mc 2048        // m-chunk (w buffer sized for one chunk)
#define NCHUNK 4

#define PI_F 3.14159265358979323846f
#define INV_SQRT_PI 0.5641895835477563f
#define TINY_F 1.17549435e-38f
#define EPS_TOTAL 1e-3f

// Workspace layout (float offsets). Total ~10.8 MB (proven-safe < Round-1's 11.3 MB).
#define WS_OUTACC 0
#define WS_DEN   (Bq*Ss*2)
#define WS_Z2    (WS_DEN + Bq)
#define WS_INVD  (WS_Z2 + Bq)
#define WS_INVDJ (WS_INVD + Bq)
#define WS_C1    (WS_INVDJ + Mm)
#define WS_C2    (WS_C1 + Mm)
#define WS_ZJ2   (WS_C2 + Mm)
#define WS_ISP   (WS_ZJ2 + Mm)
#define WS_ISQ   (WS_ISP + Mm)
#define WS_COEF  (WS_ISQ + Mm)
#define WS_SCALE (WS_COEF + Mm)
#define WS_W     (WS_SCALE + Mm)   // Bq*Mc floats

// ---------------- prep over b: 1/|d|, |z|^2 ----------------
__global__ void cpsf_prep_b(const float* __restrict__ z_re, const float* __restrict__ z_im,
                            const float* __restrict__ d_re, const float* __restrict__ d_im,
                            float* __restrict__ ws)
{
    const int b = blockIdx.x * 4 + (threadIdx.x >> 6);
    const int l = threadIdx.x & 63;
    const int o = b * Nn;
    float dr0 = d_re[o + l], dr1 = d_re[o + l + 64];
    float di0 = d_im[o + l], di1 = d_im[o + l + 64];
    float zr0 = z_re[o + l], zr1 = z_re[o + l + 64];
    float zi0 = z_im[o + l], zi1 = z_im[o + l + 64];
    float sd = dr0*dr0 + di0*di0 + dr1*dr1 + di1*di1;
    float sz = zr0*zr0 + zi0*zi0 + zr1*zr1 + zi1*zi1;
#pragma unroll
    for (int off = 1; off < 64; off <<= 1) {
        sd += __shfl_xor(sd, off);
        sz += __shfl_xor(sz, off);
    }
    if (l == 0) {
        float nd = sqrtf(sd);
        nd = (nd == 0.0f) ? 1.0f : nd;
        ws[WS_Z2 + b] = sz;
        ws[WS_INVD + b] = 1.0f / nd;
    }
}

// ---------------- prep over m: 1/|dj|, folded constants ----------------
__global__ void cpsf_prep_m(const float* __restrict__ zj_re, const float* __restrict__ zj_im,
                            const float* __restrict__ dj_re, const float* __restrict__ dj_im,
                            const float* __restrict__ alpha, const float* __restrict__ sp_,
                            const float* __restrict__ sq_, float* __restrict__ ws)
{
    const int m = blockIdx.x * 4 + (threadIdx.x >> 6);
    const int l = threadIdx.x & 63;
    const int o = m * Nn;
    float dr0 = dj_re[o + l], dr1 = dj_re[o + l + 64];
    float di0 = dj_im[o + l], di1 = dj_im[o + l + 64];
    float zr0 = zj_re[o + l], zr1 = zj_re[o + l + 64];
    float zi0 = zj_im[o + l], zi1 = zj_im[o + l + 64];
    float snd = dr0*dr0 + di0*di0 + dr1*dr1 + di1*di1;
    float sc1 = dr0*zr0 + di0*zi0 + dr1*zr1 + di1*zi1;
    float sc2 = dr0*zi0 - di0*zr0 + dr1*zi1 - di1*zr1;
    float sz2 = zr0*zr0 + zi0*zi0 + zr1*zr1 + zi1*zi1;
#pragma unroll
    for (int off = 1; off < 64; off <<= 1) {
        snd += __shfl_xor(snd, off);
        sc1 += __shfl_xor(sc1, off);
        sc2 += __shfl_xor(sc2, off);
        sz2 += __shfl_xor(sz2, off);
    }
    if (l == 0) {
        float nd = sqrtf(snd);
        nd = (nd == 0.0f) ? 1.0f : nd;
        float inv = 1.0f / nd;
        ws[WS_INVDJ + m] = inv;
        ws[WS_C1 + m]  = sc1 * inv;
        ws[WS_C2 + m]  = sc2 * inv;
        ws[WS_ZJ2 + m] = sz2;
        float sp = fmaxf(sp_[m], TINY_F);
        float sq = fmaxf(sq_[m], TINY_F);
        float sc = sqrtf(sp / PI_F);
        ws[WS_ISP + m]   = PI_F / sp;
        ws[WS_ISQ + m]   = PI_F / sq;
        ws[WS_SCALE + m] = sc;
        ws[WS_COEF + m]  = fmaxf(alpha[m], TINY_F) * sc * INV_SQRT_PI;
    }
}

// ---------------- kernel A: 5 dot-maps + GH epilogue -> w chunk ----------------
// 64b x 64m per block, 256 threads, 4x4 pairs/thread, 5 accumulators each (80 regs).
// No live range crosses phases -> no spill.
__global__ __launch_bounds__(256, 2) void cpsf_gemm_w(
    const float* __restrict__ z_re, const float* __restrict__ z_im,
    const float* __restrict__ d_re, const float* __restrict__ d_im,
    const float* __restrict__ zj_re, const float* __restrict__ zj_im,
    const float* __restrict__ dj_re, const float* __restrict__ dj_im,
    float* __restrict__ ws, int m0g)
{
    // 8 n-major planes [16 n][68 rows-padded] (stride 68 keeps b128 alignment,
    // rotates banks by 4/row: staging writes & compute reads are <=2-way = free)
    __shared__ __align__(16) float sm[8 * 1088];

    const int tid = threadIdx.x;
    const int b0 = blockIdx.y * 64;
    const int mlocal0 = blockIdx.x * 64;
    const int m0 = m0g + mlocal0;

    const int b4 = (tid >> 4) * 4;
    const int m4 = (tid & 15) * 4;
    const int row = tid >> 2;   // 0..63 (staging)
    const int j4  = tid & 3;    // 0..3  (staging)

    const float sdb = ws[WS_INVD + b0 + row];
    const float sdm = ws[WS_INVDJ + m0 + row];

    float a0[16], a1[16], a2[16], a3[16], a4[16];
#pragma unroll
    for (int i = 0; i < 16; ++i) { a0[i]=0.f; a1[i]=0.f; a2[i]=0.f; a3[i]=0.f; a4[i]=0.f; }

    for (int nk = 0; nk < Nn; nk += 16) {
        __syncthreads();
#define STAGE(P, SRC, RB, SC) { \
        float4 v = *(const float4*)((SRC) + (RB + row) * Nn + nk + j4 * 4); \
        float* d = sm + (P)*1088 + (j4*4)*68 + row; \
        d[0] = v.x * (SC); d[68] = v.y * (SC); d[136] = v.z * (SC); d[204] = v.w * (SC); }
        STAGE(0, z_re,  b0, 1.0f)
        STAGE(1, z_im,  b0, 1.0f)
        STAGE(2, d_re,  b0, sdb)
        STAGE(3, d_im,  b0, sdb)
        STAGE(4, dj_re, m0, sdm)
        STAGE(5, dj_im, m0, sdm)
        STAGE(6, zj_re, m0, 1.0f)
        STAGE(7, zj_im, m0, 1.0f)
#undef STAGE
        __syncthreads();
#pragma unroll 2
        for (int j = 0; j < 16; ++j) {
            float zr[4], zi[4], ur[4], ui[4], mr[4], mi[4], qr[4], qi[4];
            const int ob = j * 68 + b4;
            const int om = j * 68 + m4;
            *(float4*)zr = *(const float4*)(sm + 0*1088 + ob);
            *(float4*)zi = *(const float4*)(sm + 1*1088 + ob);
            *(float4*)ur = *(const float4*)(sm + 2*1088 + ob);
            *(float4*)ui = *(const float4*)(sm + 3*1088 + ob);
            *(float4*)mr = *(const float4*)(sm + 4*1088 + om);
            *(float4*)mi = *(const float4*)(sm + 5*1088 + om);
            *(float4*)qr = *(const float4*)(sm + 6*1088 + om);
            *(float4*)qi = *(const float4*)(sm + 7*1088 + om);
#pragma unroll
            for (int bb = 0; bb < 4; ++bb) {
#pragma unroll
                for (int mm = 0; mm < 4; ++mm) {
                    int x = bb * 4 + mm;
                    a0[x] += zr[bb] * mr[mm] + zi[bb] * mi[mm];  // pr raw
                    a1[x] += zi[bb] * mr[mm] - zr[bb] * mi[mm];  // pi raw
                    a2[x] += zr[bb] * qr[mm] + zi[bb] * qi[mm];  // z.zj
                    a3[x] += ur[bb] * mr[mm] + ui[bb] * mi[mm];  // ar
                    a4[x] += ui[bb] * mr[mm] - ur[bb] * mi[mm];  // ai
                }
            }
        }
    }
    __syncthreads();

    const float GT[8] = {-2.9306374202572440f, -1.9816567566958429f,
                         -1.1571937124467802f, -0.3811869902073221f,
                          0.3811869902073221f,  1.1571937124467802f,
                          1.9816567566958429f,  2.9306374202572440f};
    const float GW[8] = {1.9960407221136762e-04f, 1.7077983007413475e-02f,
                         2.0780232581489188e-01f, 6.6114701255824129e-01f,
                         6.6114701255824129e-01f, 2.0780232581489188e-01f,
                         1.7077983007413475e-02f, 1.9960407221136762e-04f};

    float z2b[4];
#pragma unroll
    for (int bb = 0; bb < 4; ++bb) z2b[bb] = ws[WS_Z2 + b0 + b4 + bb];

    float wout[16];
    float densum[4] = {0.f, 0.f, 0.f, 0.f};
#pragma unroll
    for (int mm = 0; mm < 4; ++mm) {
        int mg = m0 + m4 + mm;
        float c1  = ws[WS_C1 + mg],  c2  = ws[WS_C2 + mg];
        float zj2 = ws[WS_ZJ2 + mg], isp = ws[WS_ISP + mg];
        float isq = ws[WS_ISQ + mg], cf  = ws[WS_COEF + mg];
        float sc  = ws[WS_SCALE + mg];
#pragma unroll
        for (int bb = 0; bb < 4; ++bb) {
            int x = bb * 4 + mm;
            float prv = a0[x] - c1;
            float piv = a1[x] - c2;
            float dz2 = z2b[bb] + zj2 - 2.0f * a2[x];
            float perp2 = fmaxf(dz2 - prv * prv - piv * piv, 0.0f);
            float basee = -(isq * perp2 + isp * piv * piv);
            float rho = 0.0f;
#pragma unroll
            for (int k = 0; k < 8; ++k) {
                float dd = prv - sc * GT[k];
                rho = fmaf(GW[k], __expf(basee - isp * dd * dd), rho);
            }
            float arv = a3[x], aiv = a4[x];
            float wv = cf * (arv * arv + aiv * aiv) * rho;
            wout[x] = wv;
            densum[bb] += wv;
        }
    }
    // write w chunk [b][mlocal], coalesced float4
    float* wch = ws + WS_W;
#pragma unroll
    for (int bb = 0; bb < 4; ++bb)
        *(float4*)(wch + (b0 + b4 + bb) * Mc + mlocal0 + m4) = *(float4*)(wout + bb * 4);
    // den partial reduce (reuse sm after barrier above)
#pragma unroll
    for (int bb = 0; bb < 4; ++bb) sm[(b4 + bb) * 17 + (tid & 15)] = densum[bb];
    __syncthreads();
    if (tid < 64) {
        float s = 0.0f;
#pragma unroll
        for (int l = 0; l < 16; ++l) s += sm[tid * 17 + l];
        atomicAdd(ws + WS_DEN + b0 + tid, s);
    }
}

// ---------------- kernel B: out_acc += w_chunk @ T_chunk ----------------
// block: 64 b x 64 cols (one of T_re/T_im, one s-quarter), over 1024 m.
__global__ __launch_bounds__(256, 4) void cpsf_gemm_out(
    const float* __restrict__ T_re, const float* __restrict__ T_im,
    float* __restrict__ ws, int m0g)
{
    __shared__ __align__(16) float sm[2 * 32 * 68];
    float* wl = sm;            // [32 m][68 b-padded]
    float* tl = sm + 32 * 68;  // [32 m][68 s-padded]

    const int tid = threadIdx.x;
    const int cg = blockIdx.x;              // 0..7: (re/im) x s-quarter
    const int b0 = blockIdx.y * 64;
    const int msub = blockIdx.z;            // 0..1
    const float* Tx = (cg & 4) ? T_im : T_re;
    const int ri = cg >> 2;
    const int s0 = (cg & 3) * 64;
    const int b4 = (tid & 15) * 4;
    const int s4 = (tid >> 4) * 4;

    const float* wch = ws + WS_W;
    float acc[16];
#pragma unroll
    for (int i = 0; i < 16; ++i) acc[i] = 0.0f;

    const int mend = msub * 1024 + 1024;
    for (int mb = msub * 1024; mb < mend; mb += 32) {
        __syncthreads();
        // stage w 64b x 32m, transposed to m-major
#pragma unroll
        for (int it = 0; it < 2; ++it) {
            int i = tid + it * 256;
            int rowb = i >> 3, jq = i & 7;
            float4 v = *(const float4*)(wch + (b0 + rowb) * Mc + mb + jq * 4);
            float* d = wl + (jq * 4) * 68 + rowb;
            d[0] = v.x; d[68] = v.y; d[136] = v.z; d[204] = v.w;
        }
        // stage T 32m x 64s, row-major (no transpose)
#pragma unroll
        for (int it = 0; it < 2; ++it) {
            int i = tid + it * 256;
            int rowm = i >> 4, sc4 = i & 15;
            float4 v = *(const float4*)(Tx + (m0g + mb + rowm) * Ss + s0 + sc4 * 4);
            *(float4*)(tl + rowm * 68 + sc4 * 4) = v;
        }
        __syncthreads();
#pragma unroll 4
        for (int j = 0; j < 32; ++j) {
            float wv[4], tv[4];
            *(float4*)wv = *(const float4*)(wl + j * 68 + b4);
            *(float4*)tv = *(const float4*)(tl + j * 68 + s4);
#pragma unroll
            for (int bb = 0; bb < 4; ++bb)
#pragma unroll
                for (int ssi = 0; ssi < 4; ++ssi)
                    acc[bb * 4 + ssi] = fmaf(wv[bb], tv[ssi], acc[bb * 4 + ssi]);
        }
    }
    float* oa = ws + WS_OUTACC;
#pragma unroll
    for (int bb = 0; bb < 4; ++bb)
#pragma unroll
        for (int ssi = 0; ssi < 4; ++ssi)
            atomicAdd(oa + ((b0 + b4 + bb) * Ss + s0 + s4 + ssi) * 2 + ri,
                      acc[bb * 4 + ssi]);
}

// ---------------- finalize: divide by den ----------------
__global__ void cpsf_fin(const float* __restrict__ ws, float* __restrict__ out)
{
    int i = blockIdx.x * 512 + threadIdx.x;
    float den = ws[WS_DEN + (i >> 9)] + EPS_TOTAL;
    out[i] = ws[WS_OUTACC + i] / den;
}

extern "C" void kernel_launch(void* const* d_in, const int* in_sizes, int n_in,
                              void* d_out, int out_size, void* d_ws, size_t ws_size,
                              hipStream_t stream)
{
    (void)in_sizes; (void)n_in; (void)out_size; (void)ws_size;
    const float* z_re  = (const float*)d_in[0];
    const float* z_im  = (const float*)d_in[1];
    const float* d_re  = (const float*)d_in[2];
    const float* d_im  = (const float*)d_in[3];
    const float* zj_re = (const float*)d_in[4];
    const float* zj_im = (const float*)d_in[5];
    const float* dj_re = (const float*)d_in[6];
    const float* dj_im = (const float*)d_in[7];
    const float* T_re  = (const float*)d_in[8];
    const float* T_im  = (const float*)d_in[9];
    const float* alpha = (const float*)d_in[10];
    const float* s_par = (const float*)d_in[11];
    const float* s_perp= (const float*)d_in[12];
    float* ws = (float*)d_ws;

    // zero out_acc + den (ws is poisoned 0xAA before every call)
    hipMemsetAsync(d_ws, 0, (size_t)WS_Z2 * sizeof(float), stream);

    cpsf_prep_b<<<Bq / 4, 256, 0, stream>>>(z_re, z_im, d_re, d_im, ws);
    cpsf_prep_m<<<Mm / 4, 256, 0, stream>>>(zj_re, zj_im, dj_re, dj_im, alpha, s_par, s_perp, ws);

    for (int c = 0; c < NCHUNK; ++c) {
        cpsf_gemm_w<<<dim3(Mc / 64, Bq / 64), 256, 0, stream>>>(
            z_re, z_im, d_re, d_im, zj_re, zj_im, dj_re, dj_im, ws, c * Mc);
        cpsf_gemm_out<<<dim3(8, Bq / 64, 2), 256, 0, stream>>>(T_re, T_im, ws, c * Mc);
    }
    cpsf_fin<<<(Bq * Ss * 2) / 512, 512, 0, stream>>>(ws, (float*)d_out);
}

// Round 3
// 272.150 us; speedup vs baseline: 9.0037x; 3.2935x over previous
//
#include <hip/hip_runtime.h>
#include <math.h>

// Problem sizes (fixed by reference)
#define Bq 1024
#define Nn 128
#define Mm 8192
#define Ss 256

typedef _Float16 f16;
typedef _Float16 f16x8 __attribute__((ext_vector_type(8)));
typedef _Float16 f16x4 __attribute__((ext_vector_type(4)));
typedef float f32x4 __attribute__((ext_vector_type(4)));

#define PI_F 3.14159265358979323846f
#define INV_SQRT_PI 0.5641895835477563f
#define TINY_F 1.17549435e-38f
#define EPS_TOTAL 1e-3f
#define WSC 1024.0f   // w scaling so f16 w stays out of subnormals

// ---------------- prep over b: |z|^2, 1/|d| ----------------
__global__ void cpsf_prep_b(const float* __restrict__ z_re, const float* __restrict__ z_im,
                            const float* __restrict__ d_re, const float* __restrict__ d_im,
                            float* __restrict__ z2, float* __restrict__ invd)
{
    const int b = blockIdx.x * 4 + (threadIdx.x >> 6);
    const int l = threadIdx.x & 63;
    const int o = b * Nn;
    float dr0 = d_re[o + l], dr1 = d_re[o + l + 64];
    float di0 = d_im[o + l], di1 = d_im[o + l + 64];
    float zr0 = z_re[o + l], zr1 = z_re[o + l + 64];
    float zi0 = z_im[o + l], zi1 = z_im[o + l + 64];
    float sd = dr0*dr0 + di0*di0 + dr1*dr1 + di1*di1;
    float sz = zr0*zr0 + zi0*zi0 + zr1*zr1 + zi1*zi1;
#pragma unroll
    for (int off = 1; off < 64; off <<= 1) {
        sd += __shfl_xor(sd, off);
        sz += __shfl_xor(sz, off);
    }
    if (l == 0) {
        float nd = sqrtf(sd);
        nd = (nd == 0.0f) ? 1.0f : nd;
        z2[b] = sz;
        invd[b] = 1.0f / nd;
    }
}

// ---------------- prep over m: folded constants (cm[8][Mm]) ----------------
// cm rows: 0=invdj 1=c1 2=c2 3=zj2 4=isp 5=isq 6=coef 7=scale
__global__ void cpsf_prep_m(const float* __restrict__ zj_re, const float* __restrict__ zj_im,
                            const float* __restrict__ dj_re, const float* __restrict__ dj_im,
                            const float* __restrict__ alpha, const float* __restrict__ sp_,
                            const float* __restrict__ sq_, float* __restrict__ cm)
{
    const int m = blockIdx.x * 4 + (threadIdx.x >> 6);
    const int l = threadIdx.x & 63;
    const int o = m * Nn;
    float dr0 = dj_re[o + l], dr1 = dj_re[o + l + 64];
    float di0 = dj_im[o + l], di1 = dj_im[o + l + 64];
    float zr0 = zj_re[o + l], zr1 = zj_re[o + l + 64];
    float zi0 = zj_im[o + l], zi1 = zj_im[o + l + 64];
    float snd = dr0*dr0 + di0*di0 + dr1*dr1 + di1*di1;
    float sc1 = dr0*zr0 + di0*zi0 + dr1*zr1 + di1*zi1;
    float sc2 = dr0*zi0 - di0*zr0 + dr1*zi1 - di1*zr1;
    float sz2 = zr0*zr0 + zi0*zi0 + zr1*zr1 + zi1*zi1;
#pragma unroll
    for (int off = 1; off < 64; off <<= 1) {
        snd += __shfl_xor(snd, off);
        sc1 += __shfl_xor(sc1, off);
        sc2 += __shfl_xor(sc2, off);
        sz2 += __shfl_xor(sz2, off);
    }
    if (l == 0) {
        float nd = sqrtf(snd);
        nd = (nd == 0.0f) ? 1.0f : nd;
        float inv = 1.0f / nd;
        cm[0*Mm + m] = inv;
        cm[1*Mm + m] = sc1 * inv;
        cm[2*Mm + m] = sc2 * inv;
        cm[3*Mm + m] = sz2;
        float sp = fmaxf(sp_[m], TINY_F);
        float sq = fmaxf(sq_[m], TINY_F);
        float sc = sqrtf(sp / PI_F);
        cm[4*Mm + m] = PI_F / sp;
        cm[5*Mm + m] = PI_F / sq;
        cm[6*Mm + m] = fmaxf(alpha[m], TINY_F) * sc * INV_SQRT_PI;
        cm[7*Mm + m] = sc;
    }
}

// ---------------- pack A-side to f16: Az=[zr|zi], Au=[ur|ui] ----------------
__global__ void cpsf_pack_ab(const float* __restrict__ z_re, const float* __restrict__ z_im,
                             const float* __restrict__ d_re, const float* __restrict__ d_im,
                             const float* __restrict__ invd, f16* __restrict__ Az, f16* __restrict__ Au)
{
    int idx = blockIdx.x * 256 + threadIdx.x;   // Bq*64 total
    int b = idx >> 6, k4 = (idx & 63) * 4;
    float4 vz, vd;
    if (k4 < 128) {
        vz = *(const float4*)(z_re + b * Nn + k4);
        vd = *(const float4*)(d_re + b * Nn + k4);
    } else {
        vz = *(const float4*)(z_im + b * Nn + k4 - 128);
        vd = *(const float4*)(d_im + b * Nn + k4 - 128);
    }
    float s = invd[b];
    *(f16x4*)(Az + b * 256 + k4) = (f16x4){(f16)vz.x, (f16)vz.y, (f16)vz.z, (f16)vz.w};
    *(f16x4*)(Au + b * 256 + k4) = (f16x4){(f16)(vd.x*s), (f16)(vd.y*s), (f16)(vd.z*s), (f16)(vd.w*s)};
}

// ---------------- pack B-side chunk: Bp[3][Mc][256] f16 ----------------
// map0=[mr|mi], map1=[-mi|mr], map2=[qr|qi]  (mr/mi = normalized dj, q = zj)
__global__ void cpsf_pack_b1(const float* __restrict__ zj_re, const float* __restrict__ zj_im,
                             const float* __restrict__ dj_re, const float* __restrict__ dj_im,
                             const float* __restrict__ cm, f16* __restrict__ Bp,
                             int Mc, int m0g, int mshift)
{
    int idx = blockIdx.x * 256 + threadIdx.x;   // 3*Mc*64 total
    int r = idx >> 6, k4 = (idx & 63) * 4;
    int p = r >> mshift, ml = r & (Mc - 1);
    int m = m0g + ml;
    float4 v; float s;
    if (p == 0) {
        v = (k4 < 128) ? *(const float4*)(dj_re + m * Nn + k4)
                       : *(const float4*)(dj_im + m * Nn + k4 - 128);
        s = cm[m];
    } else if (p == 1) {
        if (k4 < 128) { v = *(const float4*)(dj_im + m * Nn + k4); v.x=-v.x; v.y=-v.y; v.z=-v.z; v.w=-v.w; }
        else          { v = *(const float4*)(dj_re + m * Nn + k4 - 128); }
        s = cm[m];
    } else {
        v = (k4 < 128) ? *(const float4*)(zj_re + m * Nn + k4)
                       : *(const float4*)(zj_im + m * Nn + k4 - 128);
        s = 1.0f;
    }
    *(f16x4*)(Bp + (size_t)r * 256 + k4) = (f16x4){(f16)(v.x*s), (f16)(v.y*s), (f16)(v.z*s), (f16)(v.w*s)};
}

// ---------------- pack T chunk transposed: Tt[s'=512][Mc] f16, s'=s*2+ri ----------------
__global__ void cpsf_pack_tt(const float* __restrict__ T_re, const float* __restrict__ T_im,
                             f16* __restrict__ Tt, int Mc, int m0g)
{
    __shared__ float tr[64][65], ti[64][65];
    const int mb = blockIdx.x * 64, sb = blockIdx.y * 64;
    const int tid = threadIdx.x;
    const int i0 = tid >> 6, j = tid & 63;
#pragma unroll
    for (int it = 0; it < 16; ++it) {
        int i = it * 4 + i0;
        tr[i][j] = T_re[(size_t)(m0g + mb + i) * Ss + sb + j];
        ti[i][j] = T_im[(size_t)(m0g + mb + i) * Ss + sb + j];
    }
    __syncthreads();
#pragma unroll
    for (int it = 0; it < 16; ++it) {
        int jj = it * 4 + i0;
        int sp = (sb + jj) * 2;
        Tt[(size_t)sp * Mc + mb + j]       = (f16)tr[j][jj];
        Tt[(size_t)(sp + 1) * Mc + mb + j] = (f16)ti[j][jj];
    }
}

// ---------------- MFMA kernel A: 5 dot-maps + GH epilogue -> w f16 ----------------
// Block tile 128b x 64m, 4 waves (2x2), wave tile 64b x 32m.
// K=256. Per K-step(32): 8 A-frag reads + 6 B-frag reads, 40 MFMAs.
__global__ __launch_bounds__(256, 2) void cpsf_gemm_w(
    const f16* __restrict__ Az, const f16* __restrict__ Au,
    const f16* __restrict__ Bp, const float* __restrict__ cm,
    const float* __restrict__ z2v, f16* __restrict__ wbuf,
    float* __restrict__ den, int Mc, int m0g)
{
    // LDS slots (16B each): Az [g4][128] = 512, Au = 512, B [g4][256] = 1024 (192 rows used/g)
    __shared__ __align__(16) f16 sm[2048 * 8];

    const int tid = threadIdx.x;
    const int wid = tid >> 6;
    const int lane = tid & 63;
    const int q = lane >> 4;
    const int li = lane & 15;
    const int mb0 = blockIdx.x * 64;        // chunk-local m base
    const int bb0 = blockIdx.y * 128;
    const int wb0 = (wid >> 1) * 64;
    const int wm0 = (wid & 1) * 32;

    f32x4 accP[4][2][3];   // maps 0..2 (pr_raw, pi_raw, z.zj)
    f32x4 accQ[4][2][2];   // maps 3..4 (ar, ai)
#pragma unroll
    for (int t = 0; t < 4; ++t)
#pragma unroll
        for (int u = 0; u < 2; ++u) {
#pragma unroll
            for (int p = 0; p < 3; ++p) accP[t][u][p] = (f32x4){0.f,0.f,0.f,0.f};
#pragma unroll
            for (int p = 0; p < 2; ++p) accQ[t][u][p] = (f32x4){0.f,0.f,0.f,0.f};
        }

    for (int kc = 0; kc < 256; kc += 32) {
        __syncthreads();
#pragma unroll
        for (int i = 0; i < 8; ++i) {
            int slot = tid + i * 256;
            const f16* src;
            if (slot < 512) {
                int g = slot >> 7, r = slot & 127;
                src = Az + (size_t)(bb0 + r) * 256 + kc + g * 8;
            } else if (slot < 1024) {
                int s2 = slot - 512;
                int g = s2 >> 7, r = s2 & 127;
                src = Au + (size_t)(bb0 + r) * 256 + kc + g * 8;
            } else {
                int s2 = slot - 1024;
                int g = s2 >> 8, r = s2 & 255;
                if (r > 191) r = 191;                  // dummy rows (staged, unused)
                int p = r >> 6, ml = r & 63;
                src = Bp + ((size_t)p * Mc + mb0 + ml) * 256 + kc + g * 8;
            }
            *(uint4*)(sm + slot * 8) = *(const uint4*)src;
        }
        __syncthreads();

        f16x8 az[4], au[4], bf[3][2];
#pragma unroll
        for (int t = 0; t < 4; ++t) {
            az[t] = *(const f16x8*)(sm + (q * 128 + wb0 + t * 16 + li) * 8);
            au[t] = *(const f16x8*)(sm + (512 + q * 128 + wb0 + t * 16 + li) * 8);
        }
#pragma unroll
        for (int p = 0; p < 3; ++p)
#pragma unroll
            for (int u = 0; u < 2; ++u)
                bf[p][u] = *(const f16x8*)(sm + (1024 + q * 256 + p * 64 + wm0 + u * 16 + li) * 8);

#pragma unroll
        for (int t = 0; t < 4; ++t)
#pragma unroll
            for (int u = 0; u < 2; ++u) {
#pragma unroll
                for (int p = 0; p < 3; ++p)
                    accP[t][u][p] = __builtin_amdgcn_mfma_f32_16x16x32_f16(az[t], bf[p][u], accP[t][u][p], 0, 0, 0);
#pragma unroll
                for (int p = 0; p < 2; ++p)
                    accQ[t][u][p] = __builtin_amdgcn_mfma_f32_16x16x32_f16(au[t], bf[p][u], accQ[t][u][p], 0, 0, 0);
            }
    }

    // ---------------- epilogue (fp32) ----------------
    const float GT[8] = {-2.9306374202572440f, -1.9816567566958429f,
                         -1.1571937124467802f, -0.3811869902073221f,
                          0.3811869902073221f,  1.1571937124467802f,
                          1.9816567566958429f,  2.9306374202572440f};
    const float GW[8] = {1.9960407221136762e-04f, 1.7077983007413475e-02f,
                         2.0780232581489188e-01f, 6.6114701255824129e-01f,
                         6.6114701255824129e-01f, 2.0780232581489188e-01f,
                         1.7077983007413475e-02f, 1.9960407221136762e-04f};

    float c1[2], c2[2], zj2[2], isp[2], isq[2], cf[2], scl[2];
#pragma unroll
    for (int u = 0; u < 2; ++u) {
        int mg = m0g + mb0 + wm0 + u * 16 + li;
        c1[u]  = cm[1*Mm + mg];  c2[u]  = cm[2*Mm + mg];
        zj2[u] = cm[3*Mm + mg];  isp[u] = cm[4*Mm + mg];
        isq[u] = cm[5*Mm + mg];  cf[u]  = cm[6*Mm + mg];
        scl[u] = cm[7*Mm + mg];
    }

    float dsum[4][4];
#pragma unroll
    for (int t = 0; t < 4; ++t)
#pragma unroll
        for (int r = 0; r < 4; ++r) dsum[t][r] = 0.f;

#pragma unroll
    for (int t = 0; t < 4; ++t) {
#pragma unroll
        for (int r = 0; r < 4; ++r) {
            const int b = bb0 + wb0 + t * 16 + q * 4 + r;
            const float z2b = z2v[b];
#pragma unroll
            for (int u = 0; u < 2; ++u) {
                float pr = accP[t][u][0][r] - c1[u];
                float pi = accP[t][u][1][r] - c2[u];
                float dz2 = z2b + zj2[u] - 2.0f * accP[t][u][2][r];
                float perp2 = fmaxf(dz2 - pr * pr - pi * pi, 0.0f);
                float base = -(isq[u] * perp2 + isp[u] * pi * pi);
                float rho = 0.0f;
#pragma unroll
                for (int k = 0; k < 8; ++k) {
                    float dd = pr - scl[u] * GT[k];
                    rho = fmaf(GW[k], __expf(base - isp[u] * dd * dd), rho);
                }
                float ar = accQ[t][u][0][r], ai = accQ[t][u][1][r];
                float wv = cf[u] * (ar * ar + ai * ai) * rho;
                dsum[t][r] += wv;
                wbuf[(size_t)b * Mc + mb0 + wm0 + u * 16 + li] = (f16)(wv * WSC);
            }
        }
    }
    // den: reduce across m (lane bits 0..3), atomic per b
#pragma unroll
    for (int t = 0; t < 4; ++t)
#pragma unroll
        for (int r = 0; r < 4; ++r) {
            float v = dsum[t][r];
            v += __shfl_xor(v, 1);
            v += __shfl_xor(v, 2);
            v += __shfl_xor(v, 4);
            v += __shfl_xor(v, 8);
            if (li == 0) atomicAdd(den + bb0 + wb0 + t * 16 + q * 4 + r, v);
        }
}

// ---------------- MFMA kernel B: out_acc += (sigma*w) @ Tt^T ----------------
// Block tile 128b x 128s', K-window 256 per block; grid z splits K.
__global__ __launch_bounds__(256, 2) void cpsf_gemm_out(
    const f16* __restrict__ wbuf, const f16* __restrict__ Tt,
    float* __restrict__ oacc, int Mc)
{
    __shared__ __align__(16) f16 sm[1024 * 8];   // w [g4][128] + Tt [g4][128]
    const int tid = threadIdx.x;
    const int wid = tid >> 6;
    const int lane = tid & 63;
    const int q = lane >> 4;
    const int li = lane & 15;
    const int sb0 = blockIdx.x * 128;
    const int bb0 = blockIdx.y * 128;
    const int kz0 = blockIdx.z * 256;
    const int wb0 = (wid >> 1) * 64;
    const int ws0 = (wid & 1) * 64;

    f32x4 acc[4][4];
#pragma unroll
    for (int t = 0; t < 4; ++t)
#pragma unroll
        for (int u = 0; u < 4; ++u) acc[t][u] = (f32x4){0.f,0.f,0.f,0.f};

    for (int kc = kz0; kc < kz0 + 256; kc += 32) {
        __syncthreads();
#pragma unroll
        for (int i = 0; i < 4; ++i) {
            int slot = tid + i * 256;
            const f16* src;
            if (slot < 512) {
                int g = slot >> 7, r = slot & 127;
                src = wbuf + (size_t)(bb0 + r) * Mc + kc + g * 8;
            } else {
                int s2 = slot - 512;
                int g = s2 >> 7, r = s2 & 127;
                src = Tt + (size_t)(sb0 + r) * Mc + kc + g * 8;
            }
            *(uint4*)(sm + slot * 8) = *(const uint4*)src;
        }
        __syncthreads();
        f16x8 af[4], bf[4];
#pragma unroll
        for (int t = 0; t < 4; ++t)
            af[t] = *(const f16x8*)(sm + (q * 128 + wb0 + t * 16 + li) * 8);
#pragma unroll
        for (int u = 0; u < 4; ++u)
            bf[u] = *(const f16x8*)(sm + (512 + q * 128 + ws0 + u * 16 + li) * 8);
#pragma unroll
        for (int t = 0; t < 4; ++t)
#pragma unroll
            for (int u = 0; u < 4; ++u)
                acc[t][u] = __builtin_amdgcn_mfma_f32_16x16x32_f16(af[t], bf[u], acc[t][u], 0, 0, 0);
    }
#pragma unroll
    for (int t = 0; t < 4; ++t)
#pragma unroll
        for (int u = 0; u < 4; ++u)
#pragma unroll
            for (int r = 0; r < 4; ++r)
                atomicAdd(oacc + (size_t)(bb0 + wb0 + t * 16 + q * 4 + r) * 512 + sb0 + ws0 + u * 16 + li,
                          acc[t][u][r]);
}

// ---------------- finalize ----------------
__global__ void cpsf_fin(const float* __restrict__ oacc, const float* __restrict__ den,
                         float* __restrict__ out)
{
    int i = blockIdx.x * 256 + threadIdx.x;
    float d = (den[i >> 9] + EPS_TOTAL) * WSC;
    out[i] = oacc[i] / d;
}

extern "C" void kernel_launch(void* const* d_in, const int* in_sizes, int n_in,
                              void* d_out, int out_size, void* d_ws, size_t ws_size,
                              hipStream_t stream)
{
    (void)in_sizes; (void)n_in; (void)out_size;
    const float* z_re  = (const float*)d_in[0];
    const float* z_im  = (const float*)d_in[1];
    const float* d_re  = (const float*)d_in[2];
    const float* d_im  = (const float*)d_in[3];
    const float* zj_re = (const float*)d_in[4];
    const float* zj_im = (const float*)d_in[5];
    const float* dj_re = (const float*)d_in[6];
    const float* dj_im = (const float*)d_in[7];
    const float* T_re  = (const float*)d_in[8];
    const float* T_im  = (const float*)d_in[9];
    const float* alpha = (const float*)d_in[10];
    const float* s_par = (const float*)d_in[11];
    const float* s_perp= (const float*)d_in[12];

    // workspace layout (bytes)
    char* w8 = (char*)d_ws;
    const size_t o_out  = 0;
    const size_t o_den  = o_out + (size_t)Bq * 512 * 4;   // 2 MB
    const size_t o_z2   = o_den + 4096;
    const size_t o_invd = o_z2 + 4096;
    const size_t o_cm   = o_invd + 4096;
    const size_t o_az   = o_cm + (size_t)8 * Mm * 4;      // 256 KB
    const size_t o_au   = o_az + (size_t)Bq * 256 * 2;
    const size_t o_ch   = o_au + (size_t)Bq * 256 * 2;
    // per-chunk: Bp 1536*Mc + Tt 1024*Mc + w 2048*Mc = 4608*Mc bytes
    int Mc = 512;
    if      (o_ch + (size_t)4608 * 8192 <= ws_size) Mc = 8192;
    else if (o_ch + (size_t)4608 * 4096 <= ws_size) Mc = 4096;
    else if (o_ch + (size_t)4608 * 2048 <= ws_size) Mc = 2048;
    else if (o_ch + (size_t)4608 * 1024 <= ws_size) Mc = 1024;
    int mshift = 31 - __builtin_clz((unsigned)Mc);

    float* oacc = (float*)(w8 + o_out);
    float* den  = (float*)(w8 + o_den);
    float* z2   = (float*)(w8 + o_z2);
    float* invd = (float*)(w8 + o_invd);
    float* cm   = (float*)(w8 + o_cm);
    f16*   Az   = (f16*)(w8 + o_az);
    f16*   Au   = (f16*)(w8 + o_au);
    f16*   Bp   = (f16*)(w8 + o_ch);
    f16*   Tt   = (f16*)(w8 + o_ch + (size_t)1536 * Mc);
    f16*   wb   = (f16*)(w8 + o_ch + (size_t)2560 * Mc);

    hipMemsetAsync(d_ws, 0, o_z2, stream);   // zero out_acc + den

    cpsf_prep_b<<<Bq / 4, 256, 0, stream>>>(z_re, z_im, d_re, d_im, z2, invd);
    cpsf_prep_m<<<Mm / 4, 256, 0, stream>>>(zj_re, zj_im, dj_re, dj_im, alpha, s_par, s_perp, cm);
    cpsf_pack_ab<<<(Bq * 64) / 256, 256, 0, stream>>>(z_re, z_im, d_re, d_im, invd, Az, Au);

    for (int m0 = 0; m0 < Mm; m0 += Mc) {
        cpsf_pack_b1<<<(3 * Mc * 64) / 256, 256, 0, stream>>>(zj_re, zj_im, dj_re, dj_im,
                                                              cm, Bp, Mc, m0, mshift);
        cpsf_pack_tt<<<dim3(Mc / 64, Ss / 64), 256, 0, stream>>>(T_re, T_im, Tt, Mc, m0);
        cpsf_gemm_w<<<dim3(Mc / 64, Bq / 128), 256, 0, stream>>>(Az, Au, Bp, cm, z2, wb, den, Mc, m0);
        cpsf_gemm_out<<<dim3(4, Bq / 128, Mc / 256), 256, 0, stream>>>(wb, Tt, oacc, Mc);
    }
    cpsf_fin<<<(Bq * 512) / 256, 256, 0, stream>>>(oacc, den, (float*)d_out);
}

// Round 4
// 247.861 us; speedup vs baseline: 9.8860x; 1.0980x over previous
//
#include <hip/hip_runtime.h>
#include <math.h>

// Problem sizes (fixed by reference)
#define Bq 1024
#define Nn 128
#define Mm 8192
#define Ss 256

typedef _Float16 f16;
typedef _Float16 f16x8 __attribute__((ext_vector_type(8)));
typedef _Float16 f16x4 __attribute__((ext_vector_type(4)));
typedef float f32x4 __attribute__((ext_vector_type(4)));

#define PI_F 3.14159265358979323846f
#define INV_SQRT_PI 0.5641895835477563f
#define TINY_F 1.17549435e-38f
#define EPS_TOTAL 1e-3f
#define WSC 1024.0f   // w scaling so f16 w stays out of subnormals

// async global->LDS copy, 16B per lane; LDS dest = wave-uniform base + lane*16
#define GLOAD16(g, l) \
    __builtin_amdgcn_global_load_lds((const __attribute__((address_space(1))) void*)(g), \
                                     (__attribute__((address_space(3))) void*)(l), 16, 0, 0)

// ---------------- prep over b: |z|^2, 1/|d| ----------------
__global__ void cpsf_prep_b(const float* __restrict__ z_re, const float* __restrict__ z_im,
                            const float* __restrict__ d_re, const float* __restrict__ d_im,
                            float* __restrict__ z2, float* __restrict__ invd)
{
    const int b = blockIdx.x * 4 + (threadIdx.x >> 6);
    const int l = threadIdx.x & 63;
    const int o = b * Nn;
    float dr0 = d_re[o + l], dr1 = d_re[o + l + 64];
    float di0 = d_im[o + l], di1 = d_im[o + l + 64];
    float zr0 = z_re[o + l], zr1 = z_re[o + l + 64];
    float zi0 = z_im[o + l], zi1 = z_im[o + l + 64];
    float sd = dr0*dr0 + di0*di0 + dr1*dr1 + di1*di1;
    float sz = zr0*zr0 + zi0*zi0 + zr1*zr1 + zi1*zi1;
#pragma unroll
    for (int off = 1; off < 64; off <<= 1) {
        sd += __shfl_xor(sd, off);
        sz += __shfl_xor(sz, off);
    }
    if (l == 0) {
        float nd = sqrtf(sd);
        nd = (nd == 0.0f) ? 1.0f : nd;
        z2[b] = sz;
        invd[b] = 1.0f / nd;
    }
}

// ---------------- prep over m: folded constants (cm[8][Mm]) ----------------
// cm rows: 0=invdj 1=c1 2=c2 3=zj2 4=isp 5=isq 6=coef 7=scale
__global__ void cpsf_prep_m(const float* __restrict__ zj_re, const float* __restrict__ zj_im,
                            const float* __restrict__ dj_re, const float* __restrict__ dj_im,
                            const float* __restrict__ alpha, const float* __restrict__ sp_,
                            const float* __restrict__ sq_, float* __restrict__ cm)
{
    const int m = blockIdx.x * 4 + (threadIdx.x >> 6);
    const int l = threadIdx.x & 63;
    const int o = m * Nn;
    float dr0 = dj_re[o + l], dr1 = dj_re[o + l + 64];
    float di0 = dj_im[o + l], di1 = dj_im[o + l + 64];
    float zr0 = zj_re[o + l], zr1 = zj_re[o + l + 64];
    float zi0 = zj_im[o + l], zi1 = zj_im[o + l + 64];
    float snd = dr0*dr0 + di0*di0 + dr1*dr1 + di1*di1;
    float sc1 = dr0*zr0 + di0*zi0 + dr1*zr1 + di1*zi1;
    float sc2 = dr0*zi0 - di0*zr0 + dr1*zi1 - di1*zr1;
    float sz2 = zr0*zr0 + zi0*zi0 + zr1*zr1 + zi1*zi1;
#pragma unroll
    for (int off = 1; off < 64; off <<= 1) {
        snd += __shfl_xor(snd, off);
        sc1 += __shfl_xor(sc1, off);
        sc2 += __shfl_xor(sc2, off);
        sz2 += __shfl_xor(sz2, off);
    }
    if (l == 0) {
        float nd = sqrtf(snd);
        nd = (nd == 0.0f) ? 1.0f : nd;
        float inv = 1.0f / nd;
        cm[0*Mm + m] = inv;
        cm[1*Mm + m] = sc1 * inv;
        cm[2*Mm + m] = sc2 * inv;
        cm[3*Mm + m] = sz2;
        float sp = fmaxf(sp_[m], TINY_F);
        float sq = fmaxf(sq_[m], TINY_F);
        float sc = sqrtf(sp / PI_F);
        cm[4*Mm + m] = PI_F / sp;
        cm[5*Mm + m] = PI_F / sq;
        cm[6*Mm + m] = fmaxf(alpha[m], TINY_F) * sc * INV_SQRT_PI;
        cm[7*Mm + m] = sc;
    }
}

// ---------------- pack A-side to f16: Az=[zr|zi], Au=[ur|ui] ----------------
__global__ void cpsf_pack_ab(const float* __restrict__ z_re, const float* __restrict__ z_im,
                             const float* __restrict__ d_re, const float* __restrict__ d_im,
                             const float* __restrict__ invd, f16* __restrict__ Az, f16* __restrict__ Au)
{
    int idx = blockIdx.x * 256 + threadIdx.x;   // Bq*64 total
    int b = idx >> 6, k4 = (idx & 63) * 4;
    float4 vz, vd;
    if (k4 < 128) {
        vz = *(const float4*)(z_re + b * Nn + k4);
        vd = *(const float4*)(d_re + b * Nn + k4);
    } else {
        vz = *(const float4*)(z_im + b * Nn + k4 - 128);
        vd = *(const float4*)(d_im + b * Nn + k4 - 128);
    }
    float s = invd[b];
    *(f16x4*)(Az + b * 256 + k4) = (f16x4){(f16)vz.x, (f16)vz.y, (f16)vz.z, (f16)vz.w};
    *(f16x4*)(Au + b * 256 + k4) = (f16x4){(f16)(vd.x*s), (f16)(vd.y*s), (f16)(vd.z*s), (f16)(vd.w*s)};
}

// ---------------- pack B-side chunk: Bp[3][Mc][256] f16 ----------------
// map0=[mr|mi], map1=[-mi|mr], map2=[qr|qi]  (mr/mi = normalized dj, q = zj)
__global__ void cpsf_pack_b1(const float* __restrict__ zj_re, const float* __restrict__ zj_im,
                             const float* __restrict__ dj_re, const float* __restrict__ dj_im,
                             const float* __restrict__ cm, f16* __restrict__ Bp,
                             int Mc, int m0g, int mshift)
{
    int idx = blockIdx.x * 256 + threadIdx.x;   // 3*Mc*64 total
    int r = idx >> 6, k4 = (idx & 63) * 4;
    int p = r >> mshift, ml = r & (Mc - 1);
    int m = m0g + ml;
    float4 v; float s;
    if (p == 0) {
        v = (k4 < 128) ? *(const float4*)(dj_re + m * Nn + k4)
                       : *(const float4*)(dj_im + m * Nn + k4 - 128);
        s = cm[m];
    } else if (p == 1) {
        if (k4 < 128) { v = *(const float4*)(dj_im + m * Nn + k4); v.x=-v.x; v.y=-v.y; v.z=-v.z; v.w=-v.w; }
        else          { v = *(const float4*)(dj_re + m * Nn + k4 - 128); }
        s = cm[m];
    } else {
        v = (k4 < 128) ? *(const float4*)(zj_re + m * Nn + k4)
                       : *(const float4*)(zj_im + m * Nn + k4 - 128);
        s = 1.0f;
    }
    *(f16x4*)(Bp + (size_t)r * 256 + k4) = (f16x4){(f16)(v.x*s), (f16)(v.y*s), (f16)(v.z*s), (f16)(v.w*s)};
}

// ---------------- pack T chunk transposed: Tt[s'=512][Mc] f16, s'=s*2+ri ----------------
__global__ void cpsf_pack_tt(const float* __restrict__ T_re, const float* __restrict__ T_im,
                             f16* __restrict__ Tt, int Mc, int m0g)
{
    __shared__ float tr[64][65], ti[64][65];
    const int mb = blockIdx.x * 64, sb = blockIdx.y * 64;
    const int tid = threadIdx.x;
    const int i0 = tid >> 6, j = tid & 63;
#pragma unroll
    for (int it = 0; it < 16; ++it) {
        int i = it * 4 + i0;
        tr[i][j] = T_re[(size_t)(m0g + mb + i) * Ss + sb + j];
        ti[i][j] = T_im[(size_t)(m0g + mb + i) * Ss + sb + j];
    }
    __syncthreads();
#pragma unroll
    for (int it = 0; it < 16; ++it) {
        int jj = it * 4 + i0;
        int sp = (sb + jj) * 2;
        Tt[(size_t)sp * Mc + mb + j]       = (f16)tr[j][jj];
        Tt[(size_t)(sp + 1) * Mc + mb + j] = (f16)ti[j][jj];
    }
}

// ---------------- MFMA kernel A: 5 dot-maps + GH epilogue -> w f16 ----------------
// Block tile 128b x 64m, 4 waves (2x2), wave tile 64b x 32m, K=256.
// LDS slots (16B = 8 f16 each): Az [g4][128]=512, Au=512, B [g4][3p][64]=768. 28 KB.
// Staging: 28 chunks of 64 slots; chunk = i*4 + wave (i=0..6), via global_load_lds.
__global__ __launch_bounds__(256, 2) void cpsf_gemm_w(
    const f16* __restrict__ Az, const f16* __restrict__ Au,
    const f16* __restrict__ Bp, const float* __restrict__ cm,
    const float* __restrict__ z2v, f16* __restrict__ wbuf,
    float* __restrict__ den, int Mc, int m0g)
{
    __shared__ __align__(16) f16 sm[1792 * 8];

    const int tid = threadIdx.x;
    const int wid = tid >> 6;
    const int lane = tid & 63;
    const int q = lane >> 4;
    const int li = lane & 15;
    const int mb0 = blockIdx.x * 64;        // chunk-local m base
    const int bb0 = blockIdx.y * 128;
    const int wb0 = (wid >> 1) * 64;
    const int wm0 = (wid & 1) * 32;

    // per-thread staging sources (one 16B slot per (i); advance 32 f16/K-step)
    const f16* gp[7];
    f16* lb[7];
#pragma unroll
    for (int i = 0; i < 7; ++i) {
        int c = i * 4 + wid;
        const f16* src;
        if (c < 8) {
            int g = c >> 1, row = (c & 1) * 64 + lane;
            src = Az + (size_t)(bb0 + row) * 256 + g * 8;
        } else if (c < 16) {
            int c2 = c - 8;
            int g = c2 >> 1, row = (c2 & 1) * 64 + lane;
            src = Au + (size_t)(bb0 + row) * 256 + g * 8;
        } else {
            int c2 = c - 16;
            int g = c2 / 3, p = c2 % 3;
            src = Bp + ((size_t)p * Mc + mb0 + lane) * 256 + g * 8;
        }
        gp[i] = src;
        lb[i] = sm + (size_t)(i * 256 + wid * 64) * 8;  // wave-uniform base
    }

    f32x4 accP[4][2][3];   // maps 0..2 (pr_raw, pi_raw, z.zj)
    f32x4 accQ[4][2][2];   // maps 3..4 (ar, ai)
#pragma unroll
    for (int t = 0; t < 4; ++t)
#pragma unroll
        for (int u = 0; u < 2; ++u) {
#pragma unroll
            for (int p = 0; p < 3; ++p) accP[t][u][p] = (f32x4){0.f,0.f,0.f,0.f};
#pragma unroll
            for (int p = 0; p < 2; ++p) accQ[t][u][p] = (f32x4){0.f,0.f,0.f,0.f};
        }

    for (int ks = 0; ks < 8; ++ks) {
        __syncthreads();                 // previous compute done before overwrite
#pragma unroll
        for (int i = 0; i < 7; ++i) {
            GLOAD16(gp[i], lb[i]);
            gp[i] += 32;
        }
        __syncthreads();                 // compiler drains vmcnt before barrier

        f16x8 az[4], au[4], bf[3][2];
#pragma unroll
        for (int t = 0; t < 4; ++t) {
            az[t] = *(const f16x8*)(sm + (size_t)(q * 128 + wb0 + t * 16 + li) * 8);
            au[t] = *(const f16x8*)(sm + (size_t)(512 + q * 128 + wb0 + t * 16 + li) * 8);
        }
#pragma unroll
        for (int p = 0; p < 3; ++p)
#pragma unroll
            for (int u = 0; u < 2; ++u)
                bf[p][u] = *(const f16x8*)(sm + (size_t)(1024 + q * 192 + p * 64 + wm0 + u * 16 + li) * 8);

#pragma unroll
        for (int t = 0; t < 4; ++t)
#pragma unroll
            for (int u = 0; u < 2; ++u) {
#pragma unroll
                for (int p = 0; p < 3; ++p)
                    accP[t][u][p] = __builtin_amdgcn_mfma_f32_16x16x32_f16(az[t], bf[p][u], accP[t][u][p], 0, 0, 0);
#pragma unroll
                for (int p = 0; p < 2; ++p)
                    accQ[t][u][p] = __builtin_amdgcn_mfma_f32_16x16x32_f16(au[t], bf[p][u], accQ[t][u][p], 0, 0, 0);
            }
    }

    // ---------------- epilogue (fp32) ----------------
    const float GT[8] = {-2.9306374202572440f, -1.9816567566958429f,
                         -1.1571937124467802f, -0.3811869902073221f,
                          0.3811869902073221f,  1.1571937124467802f,
                          1.9816567566958429f,  2.9306374202572440f};
    const float GW[8] = {1.9960407221136762e-04f, 1.7077983007413475e-02f,
                         2.0780232581489188e-01f, 6.6114701255824129e-01f,
                         6.6114701255824129e-01f, 2.0780232581489188e-01f,
                         1.7077983007413475e-02f, 1.9960407221136762e-04f};

    float c1[2], c2[2], zj2[2], isp[2], isq[2], cf[2], scl[2];
#pragma unroll
    for (int u = 0; u < 2; ++u) {
        int mg = m0g + mb0 + wm0 + u * 16 + li;
        c1[u]  = cm[1*Mm + mg];  c2[u]  = cm[2*Mm + mg];
        zj2[u] = cm[3*Mm + mg];  isp[u] = cm[4*Mm + mg];
        isq[u] = cm[5*Mm + mg];  cf[u]  = cm[6*Mm + mg];
        scl[u] = cm[7*Mm + mg];
    }

    float dsum[4][4];
#pragma unroll
    for (int t = 0; t < 4; ++t)
#pragma unroll
        for (int r = 0; r < 4; ++r) dsum[t][r] = 0.f;

#pragma unroll
    for (int t = 0; t < 4; ++t) {
#pragma unroll
        for (int r = 0; r < 4; ++r) {
            const int b = bb0 + wb0 + t * 16 + q * 4 + r;
            const float z2b = z2v[b];
#pragma unroll
            for (int u = 0; u < 2; ++u) {
                float pr = accP[t][u][0][r] - c1[u];
                float pi = accP[t][u][1][r] - c2[u];
                float dz2 = z2b + zj2[u] - 2.0f * accP[t][u][2][r];
                float perp2 = fmaxf(dz2 - pr * pr - pi * pi, 0.0f);
                float base = -(isq[u] * perp2 + isp[u] * pi * pi);
                float rho = 0.0f;
#pragma unroll
                for (int k = 0; k < 8; ++k) {
                    float dd = pr - scl[u] * GT[k];
                    rho = fmaf(GW[k], __expf(base - isp[u] * dd * dd), rho);
                }
                float ar = accQ[t][u][0][r], ai = accQ[t][u][1][r];
                float wv = cf[u] * (ar * ar + ai * ai) * rho;
                dsum[t][r] += wv;
                wbuf[(size_t)b * Mc + mb0 + wm0 + u * 16 + li] = (f16)(wv * WSC);
            }
        }
    }
    // den: reduce across m (lane bits 0..3), atomic per b
#pragma unroll
    for (int t = 0; t < 4; ++t)
#pragma unroll
        for (int r = 0; r < 4; ++r) {
            float v = dsum[t][r];
            v += __shfl_xor(v, 1);
            v += __shfl_xor(v, 2);
            v += __shfl_xor(v, 4);
            v += __shfl_xor(v, 8);
            if (li == 0) atomicAdd(den + bb0 + wb0 + t * 16 + q * 4 + r, v);
        }
}

// ---------------- MFMA kernel B: out_acc += w @ Tt^T ----------------
// Block tile 128b x 128s', K-window Kw; register acc, one atomic pass.
// LDS: w [g4][128]=512 slots + Tt [g4][128]=512 slots = 16 KB.
__global__ __launch_bounds__(256, 3) void cpsf_gemm_out(
    const f16* __restrict__ wbuf, const f16* __restrict__ Tt,
    float* __restrict__ oacc, int Mc, int Kw)
{
    __shared__ __align__(16) f16 sm[1024 * 8];
    const int tid = threadIdx.x;
    const int wid = tid >> 6;
    const int lane = tid & 63;
    const int q = lane >> 4;
    const int li = lane & 15;
    const int sb0 = blockIdx.x * 128;
    const int bb0 = blockIdx.y * 128;
    const int kz0 = blockIdx.z * Kw;
    const int wb0 = (wid >> 1) * 64;
    const int ws0 = (wid & 1) * 64;

    const f16* gp[4];
    f16* lb[4];
#pragma unroll
    for (int i = 0; i < 4; ++i) {
        int c = i * 4 + wid;
        const f16* src;
        if (c < 8) {
            int g = c >> 1, row = (c & 1) * 64 + lane;
            src = wbuf + (size_t)(bb0 + row) * Mc + kz0 + g * 8;
        } else {
            int c2 = c - 8;
            int g = c2 >> 1, row = (c2 & 1) * 64 + lane;
            src = Tt + (size_t)(sb0 + row) * Mc + kz0 + g * 8;
        }
        gp[i] = src;
        lb[i] = sm + (size_t)(i * 256 + wid * 64) * 8;
    }

    f32x4 acc[4][4];
#pragma unroll
    for (int t = 0; t < 4; ++t)
#pragma unroll
        for (int u = 0; u < 4; ++u) acc[t][u] = (f32x4){0.f,0.f,0.f,0.f};

    for (int kc = 0; kc < Kw; kc += 32) {
        __syncthreads();
#pragma unroll
        for (int i = 0; i < 4; ++i) {
            GLOAD16(gp[i], lb[i]);
            gp[i] += 32;
        }
        __syncthreads();
        f16x8 af[4], bf[4];
#pragma unroll
        for (int t = 0; t < 4; ++t)
            af[t] = *(const f16x8*)(sm + (size_t)(q * 128 + wb0 + t * 16 + li) * 8);
#pragma unroll
        for (int u = 0; u < 4; ++u)
            bf[u] = *(const f16x8*)(sm + (size_t)(512 + q * 128 + ws0 + u * 16 + li) * 8);
#pragma unroll
        for (int t = 0; t < 4; ++t)
#pragma unroll
            for (int u = 0; u < 4; ++u)
                acc[t][u] = __builtin_amdgcn_mfma_f32_16x16x32_f16(af[t], bf[u], acc[t][u], 0, 0, 0);
    }
#pragma unroll
    for (int t = 0; t < 4; ++t)
#pragma unroll
        for (int u = 0; u < 4; ++u)
#pragma unroll
            for (int r = 0; r < 4; ++r)
                atomicAdd(oacc + (size_t)(bb0 + wb0 + t * 16 + q * 4 + r) * 512 + sb0 + ws0 + u * 16 + li,
                          acc[t][u][r]);
}

// ---------------- finalize ----------------
__global__ void cpsf_fin(const float* __restrict__ oacc, const float* __restrict__ den,
                         float* __restrict__ out)
{
    int i = blockIdx.x * 256 + threadIdx.x;
    float d = (den[i >> 9] + EPS_TOTAL) * WSC;
    out[i] = oacc[i] / d;
}

extern "C" void kernel_launch(void* const* d_in, const int* in_sizes, int n_in,
                              void* d_out, int out_size, void* d_ws, size_t ws_size,
                              hipStream_t stream)
{
    (void)in_sizes; (void)n_in; (void)out_size;
    const float* z_re  = (const float*)d_in[0];
    const float* z_im  = (const float*)d_in[1];
    const float* d_re  = (const float*)d_in[2];
    const float* d_im  = (const float*)d_in[3];
    const float* zj_re = (const float*)d_in[4];
    const float* zj_im = (const float*)d_in[5];
    const float* dj_re = (const float*)d_in[6];
    const float* dj_im = (const float*)d_in[7];
    const float* T_re  = (const float*)d_in[8];
    const float* T_im  = (const float*)d_in[9];
    const float* alpha = (const float*)d_in[10];
    const float* s_par = (const float*)d_in[11];
    const float* s_perp= (const float*)d_in[12];

    // workspace layout (bytes)
    char* w8 = (char*)d_ws;
    const size_t o_out  = 0;
    const size_t o_den  = o_out + (size_t)Bq * 512 * 4;   // 2 MB
    const size_t o_z2   = o_den + 4096;
    const size_t o_invd = o_z2 + 4096;
    const size_t o_cm   = o_invd + 4096;
    const size_t o_az   = o_cm + (size_t)8 * Mm * 4;      // 256 KB
    const size_t o_au   = o_az + (size_t)Bq * 256 * 2;
    const size_t o_ch   = o_au + (size_t)Bq * 256 * 2;
    // per-chunk: Bp 1536*Mc + Tt 1024*Mc + w 2048*Mc = 4608*Mc bytes
    int Mc = 512;
    if      (o_ch + (size_t)4608 * 8192 <= ws_size) Mc = 8192;
    else if (o_ch + (size_t)4608 * 4096 <= ws_size) Mc = 4096;
    else if (o_ch + (size_t)4608 * 2048 <= ws_size) Mc = 2048;
    else if (o_ch + (size_t)4608 * 1024 <= ws_size) Mc = 1024;
    int mshift = 31 - __builtin_clz((unsigned)Mc);
    int zs = Mc / 1024; if (zs < 1) zs = 1;
    int Kw = Mc / zs;

    float* oacc = (float*)(w8 + o_out);
    float* den  = (float*)(w8 + o_den);
    float* z2   = (float*)(w8 + o_z2);
    float* invd = (float*)(w8 + o_invd);
    float* cm   = (float*)(w8 + o_cm);
    f16*   Az   = (f16*)(w8 + o_az);
    f16*   Au   = (f16*)(w8 + o_au);
    f16*   Bp   = (f16*)(w8 + o_ch);
    f16*   Tt   = (f16*)(w8 + o_ch + (size_t)1536 * Mc);
    f16*   wb   = (f16*)(w8 + o_ch + (size_t)2560 * Mc);

    hipMemsetAsync(d_ws, 0, o_z2, stream);   // zero out_acc + den

    cpsf_prep_b<<<Bq / 4, 256, 0, stream>>>(z_re, z_im, d_re, d_im, z2, invd);
    cpsf_prep_m<<<Mm / 4, 256, 0, stream>>>(zj_re, zj_im, dj_re, dj_im, alpha, s_par, s_perp, cm);
    cpsf_pack_ab<<<(Bq * 64) / 256, 256, 0, stream>>>(z_re, z_im, d_re, d_im, invd, Az, Au);

    for (int m0 = 0; m0 < Mm; m0 += Mc) {
        cpsf_pack_b1<<<(3 * Mc * 64) / 256, 256, 0, stream>>>(zj_re, zj_im, dj_re, dj_im,
                                                              cm, Bp, Mc, m0, mshift);
        cpsf_pack_tt<<<dim3(Mc / 64, Ss / 64), 256, 0, stream>>>(T_re, T_im, Tt, Mc, m0);
        cpsf_gemm_w<<<dim3(Mc / 64, Bq / 128), 256, 0, stream>>>(Az, Au, Bp, cm, z2, wb, den, Mc, m0);
        cpsf_gemm_out<<<dim3(4, Bq / 128, zs), 256, 0, stream>>>(wb, Tt, oacc, Mc, Kw);
    }
    cpsf_fin<<<(Bq * 512) / 256, 256, 0, stream>>>(oacc, den, (float*)d_out);
}